// Round 1
// baseline (42.742 us; speedup 1.0000x reference)
//
#include <hip/hip_runtime.h>
#include <math.h>

#define QN 32
#define SN 128
#define EN 256
#define BN 64
#define IC 8            // i-chunks per q in kern_edq (each block covers 16 i)
#define SCALE_F 20.0f

// ws layout: edq_part[QN*IC] floats, then xy[QN*BN] floats  (~9 KB total)

__device__ __forceinline__ float l1_4(float4 a, float4 b) {
    return fabsf(a.x - b.x) + fabsf(a.y - b.y) + fabsf(a.z - b.z) + fabsf(a.w - b.w);
}

// Kernel A: edq_part[q*IC + chunk] = sum over i in chunk of m_i * sum_j m_j * L1(a_i, a_j)
__global__ __launch_bounds__(256) void kern_edq(const float* __restrict__ A,
                                                const int* __restrict__ M,
                                                float* __restrict__ edq_part) {
    const int q = blockIdx.x, chunk = blockIdx.y;
    const int wave = threadIdx.x >> 6, lane = threadIdx.x & 63;
    __shared__ float mf[SN];
    __shared__ float red[4];
    if (threadIdx.x < SN) mf[threadIdx.x] = (float)M[q * SN + threadIdx.x];
    __syncthreads();

    const float* Aq = A + (size_t)q * SN * EN;
    const int ibase = chunk * 16 + wave * 4;   // 4 i-rows per wave

    float4 ai[4];
    float  mi[4];
#pragma unroll
    for (int k = 0; k < 4; ++k) {
        ai[k] = *(const float4*)(Aq + (size_t)(ibase + k) * EN + lane * 4);
        mi[k] = mf[ibase + k];
    }

    float acc[4] = {0.f, 0.f, 0.f, 0.f};
    for (int j = 0; j < SN; ++j) {
        float4 aj = *(const float4*)(Aq + (size_t)j * EN + lane * 4);
        float  mj = mf[j];
#pragma unroll
        for (int k = 0; k < 4; ++k) acc[k] = fmaf(mj, l1_4(ai[k], aj), acc[k]);
    }

    float tot = mi[0] * acc[0] + mi[1] * acc[1] + mi[2] * acc[2] + mi[3] * acc[3];
#pragma unroll
    for (int off = 32; off; off >>= 1) tot += __shfl_down(tot, off, 64);
    if (lane == 0) red[wave] = tot;
    __syncthreads();
    if (threadIdx.x == 0)
        edq_part[q * IC + chunk] = red[0] + red[1] + red[2] + red[3];
}

// Kernel B: xy[q*BN + b] = sum_s m_s * L1(a[q,s], cand[b])   (raw, un-normalized)
__global__ __launch_bounds__(256) void kern_xy(const float* __restrict__ A,
                                               const float* __restrict__ Cd,
                                               const int* __restrict__ M,
                                               float* __restrict__ xy) {
    const int q = blockIdx.x, chunk = blockIdx.y;
    const int wave = threadIdx.x >> 6, lane = threadIdx.x & 63;
    __shared__ float mf[SN];
    if (threadIdx.x < SN) mf[threadIdx.x] = (float)M[q * SN + threadIdx.x];
    __syncthreads();

    const int bbase = chunk * 16 + wave * 4;   // 4 b-rows per wave
    float4 cb[4];
#pragma unroll
    for (int k = 0; k < 4; ++k)
        cb[k] = *(const float4*)(Cd + (size_t)(bbase + k) * EN + lane * 4);

    float acc[4] = {0.f, 0.f, 0.f, 0.f};
    const float* Aq = A + (size_t)q * SN * EN;
    for (int s = 0; s < SN; ++s) {
        float4 as = *(const float4*)(Aq + (size_t)s * EN + lane * 4);
        float  ms = mf[s];
#pragma unroll
        for (int k = 0; k < 4; ++k) acc[k] = fmaf(ms, l1_4(as, cb[k]), acc[k]);
    }

#pragma unroll
    for (int k = 0; k < 4; ++k) {
        float t = acc[k];
#pragma unroll
        for (int off = 32; off; off >>= 1) t += __shfl_down(t, off, 64);
        if (lane == 0) xy[q * BN + bbase + k] = t;
    }
}

// Kernel C: assemble scores, per-row logsumexp over B=64 (== wave width), mean CE loss.
__global__ __launch_bounds__(256) void kern_loss(const float* __restrict__ xy,
                                                 const float* __restrict__ edq_part,
                                                 const int* __restrict__ M,
                                                 float* __restrict__ out) {
    const int wave = threadIdx.x >> 6, lane = threadIdx.x & 63;
    __shared__ float red[4];
    float lsum = 0.f;
    for (int q = wave; q < QN; q += 4) {
        // nvalid = sum of mask row
        float mv = (float)M[q * SN + lane] + (float)M[q * SN + 64 + lane];
#pragma unroll
        for (int off = 32; off; off >>= 1) mv += __shfl_xor(mv, off, 64);
        float nv    = mv;
        float valid = fmaxf(nv, 1.f);
        float vp    = fmaxf(nv * nv, 1.f);

        float ednum = 0.f;
#pragma unroll
        for (int c = 0; c < IC; ++c) ednum += edq_part[q * IC + c];
        float edq = ednum / vp;

        // lane == b  (B == 64)
        float score = -SCALE_F * (2.f * xy[q * BN + lane] / valid - edq);

        float mx = score;
#pragma unroll
        for (int off = 32; off; off >>= 1) mx = fmaxf(mx, __shfl_xor(mx, off, 64));
        float ex = expf(score - mx);
#pragma unroll
        for (int off = 32; off; off >>= 1) ex += __shfl_xor(ex, off, 64);
        float lse  = mx + logf(ex);
        float diag = __shfl(score, q, 64);
        lsum += lse - diag;
    }
    if (lane == 0) red[wave] = lsum;
    __syncthreads();
    if (threadIdx.x == 0)
        out[0] = (red[0] + red[1] + red[2] + red[3]) / (float)QN;
}

extern "C" void kernel_launch(void* const* d_in, const int* in_sizes, int n_in,
                              void* d_out, int out_size, void* d_ws, size_t ws_size,
                              hipStream_t stream) {
    const float* A  = (const float*)d_in[0];   // anchors [Q,S,E] f32
    const float* Cd = (const float*)d_in[1];   // candidates [B,E] f32
    const int*   M  = (const int*)d_in[2];     // attention_mask [Q,S] i32
    float* out = (float*)d_out;

    float* edq_part = (float*)d_ws;            // [QN*IC]
    float* xy       = edq_part + QN * IC;      // [QN*BN]

    kern_edq<<<dim3(QN, IC), 256, 0, stream>>>(A, M, edq_part);
    kern_xy <<<dim3(QN, BN / 16), 256, 0, stream>>>(A, Cd, M, xy);
    kern_loss<<<1, 256, 0, stream>>>(xy, edq_part, M, out);
}

// Round 2
// 31.136 us; speedup vs baseline: 1.3728x; 1.3728x over previous
//
#include <hip/hip_runtime.h>
#include <math.h>

#define QN 32
#define SN 128
#define EN 256
#define BN 64
#define SCALE_F 20.0f

// Fused distance kernel.
// A-part (blocks [0,512)): edq partials. q = bi&31, chunk=(bi>>5)&7, jh=bi>>8.
//   Block covers i in [chunk*16, chunk*16+16), j in [jh*64, jh*64+64).
//   edq_part[q*16 + chunk*2 + jh] = sum_i m_i sum_j m_j L1(a_i,a_j)
// B-part (blocks [512,768)): xy partials. bi2=bi-512; q=bi2&31, cc=(bi2>>5)&3, sh=bi2>>7.
//   Block covers b in [cc*16, cc*16+16), s in [sh*64, sh*64+64).
//   xy_part[sh*QN*BN + q*BN + b] = sum_s m_s L1(a_s, c_b)

__device__ __forceinline__ float l1_4(float4 a, float4 b) {
    return fabsf(a.x - b.x) + fabsf(a.y - b.y) + fabsf(a.z - b.z) + fabsf(a.w - b.w);
}

__global__ __launch_bounds__(256) void kern_dist(const float* __restrict__ A,
                                                 const float* __restrict__ Cd,
                                                 const int* __restrict__ M,
                                                 float* __restrict__ edq_part,
                                                 float* __restrict__ xy_part) {
    const int bi   = blockIdx.x;
    const int wave = threadIdx.x >> 6, lane = threadIdx.x & 63;
    __shared__ float mf[SN];
    __shared__ float red[4];

    if (bi < 512) {
        // ---------------- edq partial ----------------
        const int q = bi & 31, chunk = (bi >> 5) & 7, jh = bi >> 8;
        if (threadIdx.x < SN) mf[threadIdx.x] = (float)M[q * SN + threadIdx.x];
        __syncthreads();

        const float* Aq = A + (size_t)q * SN * EN;
        const int ibase = chunk * 16 + wave * 4;

        float4 ai[4];
        float  mi[4];
#pragma unroll
        for (int k = 0; k < 4; ++k) {
            ai[k] = *(const float4*)(Aq + (size_t)(ibase + k) * EN + lane * 4);
            mi[k] = mf[ibase + k];
        }

        float acc[4] = {0.f, 0.f, 0.f, 0.f};
        const int j0 = jh * 64;
#pragma unroll 4
        for (int j = j0; j < j0 + 64; ++j) {
            float4 aj = *(const float4*)(Aq + (size_t)j * EN + lane * 4);
            float  mj = mf[j];
#pragma unroll
            for (int k = 0; k < 4; ++k) acc[k] = fmaf(mj, l1_4(ai[k], aj), acc[k]);
        }

        float tot = mi[0] * acc[0] + mi[1] * acc[1] + mi[2] * acc[2] + mi[3] * acc[3];
#pragma unroll
        for (int off = 32; off; off >>= 1) tot += __shfl_down(tot, off, 64);
        if (lane == 0) red[wave] = tot;
        __syncthreads();
        if (threadIdx.x == 0)
            edq_part[q * 16 + chunk * 2 + jh] = red[0] + red[1] + red[2] + red[3];
    } else {
        // ---------------- xy partial ----------------
        const int bi2 = bi - 512;
        const int q = bi2 & 31, cc = (bi2 >> 5) & 3, sh = bi2 >> 7;
        if (threadIdx.x < SN) mf[threadIdx.x] = (float)M[q * SN + threadIdx.x];
        __syncthreads();

        const int bbase = cc * 16 + wave * 4;
        float4 cb[4];
#pragma unroll
        for (int k = 0; k < 4; ++k)
            cb[k] = *(const float4*)(Cd + (size_t)(bbase + k) * EN + lane * 4);

        float acc[4] = {0.f, 0.f, 0.f, 0.f};
        const float* Aq = A + (size_t)q * SN * EN;
        const int s0 = sh * 64;
#pragma unroll 4
        for (int s = s0; s < s0 + 64; ++s) {
            float4 as = *(const float4*)(Aq + (size_t)s * EN + lane * 4);
            float  ms = mf[s];
#pragma unroll
            for (int k = 0; k < 4; ++k) acc[k] = fmaf(ms, l1_4(as, cb[k]), acc[k]);
        }

#pragma unroll
        for (int k = 0; k < 4; ++k) {
            float t = acc[k];
#pragma unroll
            for (int off = 32; off; off >>= 1) t += __shfl_down(t, off, 64);
            if (lane == 0) xy_part[sh * QN * BN + q * BN + bbase + k] = t;
        }
    }
}

// Kernel C: assemble scores, per-row logsumexp over B=64 (== wave width), mean CE loss.
__global__ __launch_bounds__(256) void kern_loss(const float* __restrict__ xy_part,
                                                 const float* __restrict__ edq_part,
                                                 const int* __restrict__ M,
                                                 float* __restrict__ out) {
    const int wave = threadIdx.x >> 6, lane = threadIdx.x & 63;
    __shared__ float red[4];
    float lsum = 0.f;
    for (int q = wave; q < QN; q += 4) {
        float mv = (float)M[q * SN + lane] + (float)M[q * SN + 64 + lane];
#pragma unroll
        for (int off = 32; off; off >>= 1) mv += __shfl_xor(mv, off, 64);
        float nv    = mv;
        float valid = fmaxf(nv, 1.f);
        float vp    = fmaxf(nv * nv, 1.f);

        float ednum = 0.f;
#pragma unroll
        for (int c = 0; c < 16; ++c) ednum += edq_part[q * 16 + c];
        float edq = ednum / vp;

        float xv = xy_part[q * BN + lane] + xy_part[QN * BN + q * BN + lane];
        float score = -SCALE_F * (2.f * xv / valid - edq);

        float mx = score;
#pragma unroll
        for (int off = 32; off; off >>= 1) mx = fmaxf(mx, __shfl_xor(mx, off, 64));
        float ex = expf(score - mx);
#pragma unroll
        for (int off = 32; off; off >>= 1) ex += __shfl_xor(ex, off, 64);
        float lse  = mx + logf(ex);
        float diag = __shfl(score, q, 64);
        lsum += lse - diag;
    }
    if (lane == 0) red[wave] = lsum;
    __syncthreads();
    if (threadIdx.x == 0)
        out[0] = (red[0] + red[1] + red[2] + red[3]) / (float)QN;
}

extern "C" void kernel_launch(void* const* d_in, const int* in_sizes, int n_in,
                              void* d_out, int out_size, void* d_ws, size_t ws_size,
                              hipStream_t stream) {
    const float* A  = (const float*)d_in[0];   // anchors [Q,S,E] f32
    const float* Cd = (const float*)d_in[1];   // candidates [B,E] f32
    const int*   M  = (const int*)d_in[2];     // attention_mask [Q,S] i32
    float* out = (float*)d_out;

    float* edq_part = (float*)d_ws;                 // [QN*16]
    float* xy_part  = edq_part + QN * 16;           // [2*QN*BN]

    kern_dist<<<768, 256, 0, stream>>>(A, Cd, M, edq_part, xy_part);
    kern_loss<<<1, 256, 0, stream>>>(xy_part, edq_part, M, out);
}